// Round 2
// baseline (411.075 us; speedup 1.0000x reference)
//
#include <hip/hip_runtime.h>
#include <stdint.h>

#define NPIX 4096
#define CDIM 512

typedef _Float16 hv8 __attribute__((ext_vector_type(8)));
typedef float f32x4 __attribute__((ext_vector_type(4)));

__device__ __forceinline__ void lds_direct16(const _Float16* g, _Float16* l) {
    __builtin_amdgcn_global_load_lds(
        (const __attribute__((address_space(1))) void*)g,
        (__attribute__((address_space(3))) void*)l, 16, 0, 0);
}

// ---------------- weight fp32 -> fp16 ----------------
__global__ void cvt_w(const float* __restrict__ s0, const float* __restrict__ s1,
                      const float* __restrict__ s2, const float* __restrict__ s3,
                      _Float16* __restrict__ d0, _Float16* __restrict__ d1,
                      _Float16* __restrict__ d2, _Float16* __restrict__ d3) {
    int i = blockIdx.x * 256 + threadIdx.x;
    d0[i] = (_Float16)s0[i];
    d1[i] = (_Float16)s1[i];
    d2[i] = (_Float16)s2[i];
    d3[i] = (_Float16)s3[i];
}

// ---------------- groupnorm stats: one block per (b,g) ----------------
__global__ void stats_kernel(const float* __restrict__ x, float* __restrict__ stats) {
    int idx = blockIdx.x;
    const float4* base = (const float4*)(x + (long)idx * 16 * NPIX);
    int tid = threadIdx.x;
    float s = 0.f, sq = 0.f;
    for (int it = 0; it < 64; ++it) {
        float4 f = base[it * 256 + tid];
        s  += f.x + f.y + f.z + f.w;
        sq += f.x * f.x + f.y * f.y + f.z * f.z + f.w * f.w;
    }
    __shared__ float rs[256], rq[256];
    rs[tid] = s; rq[tid] = sq;
    __syncthreads();
    for (int st = 128; st > 0; st >>= 1) {
        if (tid < st) { rs[tid] += rs[tid + st]; rq[tid] += rq[tid + st]; }
        __syncthreads();
    }
    if (tid == 0) {
        float mean = rs[0] * (1.0f / 65536.0f);
        float var  = rq[0] * (1.0f / 65536.0f) - mean * mean;
        stats[idx * 2]     = mean;
        stats[idx * 2 + 1] = rsqrtf(var + 1e-6f);
    }
}

// ---------------- normalize + transpose: hT[b][n][c] = GN(x)[b][c][n] ----------------
__global__ void normT_kernel(const float* __restrict__ x, const float* __restrict__ stats,
                             const float* __restrict__ gamma, const float* __restrict__ beta,
                             _Float16* __restrict__ hT) {
    int b = blockIdx.z, c0 = blockIdx.x * 32, n0 = blockIdx.y * 32;
    int tid = threadIdx.x;
    __shared__ float t[32][33];
    int cl = tid >> 5;
    int nl = tid & 31;
    for (int r = 0; r < 4; ++r)
        t[r * 8 + cl][nl] = x[(long)b * CDIM * NPIX + (long)(c0 + r * 8 + cl) * NPIX + n0 + nl];
    __syncthreads();
    for (int r = 0; r < 4; ++r) {
        int nr = r * 8 + cl;
        int c = c0 + nl;
        float m    = stats[(b * 32 + (c >> 4)) * 2];
        float rstd = stats[(b * 32 + (c >> 4)) * 2 + 1];
        float val = (t[nl][nr] - m) * rstd * gamma[c] + beta[c];
        hT[(long)b * NPIX * CDIM + (long)(n0 + nr) * CDIM + c] = (_Float16)val;
    }
}

// ---------------- bt-form GEMM: D[M][N] = A[M][K] * BT[N][K]^T ----------------
template<int EPI>
__launch_bounds__(256, 2)
__global__ void gemm_bt_kernel(const _Float16* __restrict__ A, const _Float16* __restrict__ BT,
                               void* __restrict__ D, const float* __restrict__ bias,
                               const float* __restrict__ resid,
                               int M, int N, int K,
                               long aBatch, long bBatch, long dBatch, long rBatch) {
    const int b = blockIdx.z;
    A  += (long)b * aBatch;
    BT += (long)b * bBatch;
    const int m0 = blockIdx.y * 128;
    const int n0 = blockIdx.x * 128;
    const int tid = threadIdx.x;
    const int l = tid & 63;
    const int w = tid >> 6;
    const int wm = (w >> 1) * 64;
    const int wn = (w & 1) * 64;
    const int lr = l & 15;
    const int lk = l >> 4;
    __shared__ __align__(16) _Float16 As[128 * 32];
    __shared__ __align__(16) _Float16 Bs[128 * 32];
    f32x4 acc[4][4] = {};
    const int nK = K >> 5;
    for (int kt = 0; kt < nK; ++kt) {
        const int kb = kt * 32;
#pragma unroll
        for (int c = 0; c < 2; ++c) {
            int chunk = c * 256 + tid;
            int row = chunk >> 2;
            int k8 = (chunk & 3) * 8;
            _Float16* ldsA = As + (size_t)(c * 256 + (tid & ~63)) * 8;
            _Float16* ldsB = Bs + (size_t)(c * 256 + (tid & ~63)) * 8;
            lds_direct16(A  + (long)(m0 + row) * K + kb + k8, ldsA);
            lds_direct16(BT + (long)(n0 + row) * K + kb + k8, ldsB);
        }
        __syncthreads();
        hv8 af[4], bfr[4];
#pragma unroll
        for (int mi = 0; mi < 4; ++mi)
            af[mi] = *(const hv8*)(As + (size_t)(wm + mi * 16 + lr) * 32 + lk * 8);
#pragma unroll
        for (int ni = 0; ni < 4; ++ni)
            bfr[ni] = *(const hv8*)(Bs + (size_t)(wn + ni * 16 + lr) * 32 + lk * 8);
#pragma unroll
        for (int mi = 0; mi < 4; ++mi)
#pragma unroll
            for (int ni = 0; ni < 4; ++ni)
                acc[mi][ni] = __builtin_amdgcn_mfma_f32_16x16x32_f16(af[mi], bfr[ni], acc[mi][ni], 0, 0, 0);
        __syncthreads();
    }
#pragma unroll
    for (int mi = 0; mi < 4; ++mi)
#pragma unroll
        for (int ni = 0; ni < 4; ++ni)
#pragma unroll
            for (int r = 0; r < 4; ++r) {
                int row = m0 + wm + mi * 16 + lk * 4 + r;
                int col = n0 + wn + ni * 16 + lr;
                float val = acc[mi][ni][r];
                if (EPI == 0) {
                    ((_Float16*)D)[(long)b * dBatch + (long)row * N + col] = (_Float16)(val + bias[col]);
                } else if (EPI == 1) {
                    ((_Float16*)D)[(long)b * dBatch + (long)row * N + col] = (_Float16)(val + bias[row]);
                } else {
                    long idx = (long)row * N + col;
                    ((float*)D)[(long)b * dBatch + idx] =
                        val + bias[row] + resid[(long)b * rBatch + idx];
                }
            }
}

// ---------------- flash attention v2 ----------------
// qT,kT [N][C] fp16, v [C][N] fp16 -> oT [N][C] fp16
// i-tile 32, j-tile 64. 8 waves: wave w -> S quadrant (iq=w>>2, jq=w&3).
// K tiles double-buffered in LDS via global_load_lds with source-side XOR swizzle.
// Q fragments and V fragments in registers; V prefetched issue-early/use-late.
__device__ __forceinline__ void attn_step(
    int jt, const _Float16* kb, const _Float16* vb,
    const _Float16* kcur, _Float16* knxt,
    const hv8 (&vcur)[4][2], hv8 (&vnxt)[4][2],
    const hv8 (&af)[16], f32x4 (&oacc)[2][4], float (&lsum)[4],
    _Float16* ps, int l, int w, int lr, int lk, int iq, int jq) {

    if (jt + 1 < 64) {
        const long j0n = (long)(jt + 1) * 64;
#pragma unroll
        for (int q = 0; q < 8; ++q) {
            int j = w * 8 + q;
            int cc = l ^ (j & 7);                       // inverse swizzle on SOURCE
            lds_direct16(kb + (j0n + j) * CDIM + cc * 8, knxt + (w * 8 + q) * 512);
        }
        __builtin_amdgcn_sched_barrier(0);
#pragma unroll
        for (int ni = 0; ni < 4; ++ni) {
            int c = w * 64 + ni * 16 + lr;
#pragma unroll
            for (int jh = 0; jh < 2; ++jh)
                vnxt[ni][jh] = *(const hv8*)(vb + (long)c * NPIX + j0n + jh * 32 + lk * 8);
        }
        __builtin_amdgcn_sched_barrier(0);
    }

    // ---- QK: one 16x16 quadrant per wave ----
    f32x4 s = {};
    {
        const char* kbase = (const char*)kcur;
        const int j = jq * 16 + lr;
        const uint32_t sw = (uint32_t)((j & 7) << 4);
#pragma unroll
        for (int kk = 0; kk < 16; ++kk) {
            uint32_t off = ((uint32_t)(j * 1024 + kk * 64 + lk * 16)) ^ sw;
            hv8 bf = *(const hv8*)(kbase + off);
            s = __builtin_amdgcn_mfma_f32_16x16x32_f16(af[kk], bf, s, 0, 0, 0);
        }
    }

    // ---- exp + P write (swizzled) ----
    const float scale = 0.044194173824159216f;   // 1/sqrt(512)
#pragma unroll
    for (int r = 0; r < 4; ++r) {
        float p = __expf(s[r] * scale);
        lsum[r] += p;
        int i = iq * 16 + lk * 4 + r;
        int j = jq * 16 + lr;
        uint32_t off = ((uint32_t)(i * 128 + j * 2)) ^ ((uint32_t)((i & 7) << 4));
        *(_Float16*)((char*)ps + off) = (_Float16)p;
    }
    // mid barrier: drain LDS writes only; K-staging stays in flight (vmcnt untouched)
    asm volatile("s_waitcnt lgkmcnt(0)" ::: "memory");
    __builtin_amdgcn_sched_barrier(0);
    __builtin_amdgcn_s_barrier();

    // ---- PV: O[32 rows][w's 64 c-cols] += P * V^T ----
#pragma unroll
    for (int jh = 0; jh < 2; ++jh) {
        hv8 pa[2];
#pragma unroll
        for (int mi = 0; mi < 2; ++mi) {
            int i = mi * 16 + lr;
            uint32_t off = ((uint32_t)(i * 128 + jh * 64 + lk * 16)) ^ ((uint32_t)((i & 7) << 4));
            pa[mi] = *(const hv8*)((const char*)ps + off);
        }
#pragma unroll
        for (int ni = 0; ni < 4; ++ni)
#pragma unroll
            for (int mi = 0; mi < 2; ++mi)
                oacc[mi][ni] = __builtin_amdgcn_mfma_f32_16x16x32_f16(pa[mi], vcur[ni][jh], oacc[mi][ni], 0, 0, 0);
    }
    __syncthreads();   // full drain: next tile's staging complete, ps reusable
}

__launch_bounds__(512, 2)
__global__ void attn_kernel(const _Float16* __restrict__ qT, const _Float16* __restrict__ kT,
                            const _Float16* __restrict__ v, _Float16* __restrict__ oT) {
    __shared__ __align__(16) _Float16 Ks[2][64 * 512];   // 128 KB, XOR-swizzled rows
    __shared__ __align__(16) _Float16 ps[32 * 64];       // 4 KB, XOR-swizzled
    __shared__ float red[8][32];
    __shared__ float redt[32];

    const int b = blockIdx.y;
    const int i0 = blockIdx.x * 32;
    const int tid = threadIdx.x;
    const int l = tid & 63, w = tid >> 6;
    const int lr = l & 15, lk = l >> 4;
    const int iq = w >> 2, jq = w & 3;

    const _Float16* qb = qT + (long)b * NPIX * CDIM;
    const _Float16* kb = kT + (long)b * NPIX * CDIM;
    const _Float16* vb = v  + (long)b * CDIM * NPIX;

    // Q fragments in registers: wave's 16 rows (iq*16+lr), all 16 k-chunks
    hv8 af[16];
    {
        const _Float16* qr = qb + (long)(i0 + iq * 16 + lr) * CDIM + lk * 8;
#pragma unroll
        for (int kk = 0; kk < 16; ++kk)
            af[kk] = *(const hv8*)(qr + kk * 32);
    }

    f32x4 oacc[2][4] = {};
    float lsum[4] = {};
    hv8 vf0[4][2], vf1[4][2];

    // prologue: stage tile 0 into Ks[0], prefetch V tile 0
    {
#pragma unroll
        for (int q = 0; q < 8; ++q) {
            int j = w * 8 + q;
            int cc = l ^ (j & 7);
            lds_direct16(kb + (long)j * CDIM + cc * 8, &Ks[0][(w * 8 + q) * 512]);
        }
        __builtin_amdgcn_sched_barrier(0);
#pragma unroll
        for (int ni = 0; ni < 4; ++ni) {
            int c = w * 64 + ni * 16 + lr;
#pragma unroll
            for (int jh = 0; jh < 2; ++jh)
                vf0[ni][jh] = *(const hv8*)(vb + (long)c * NPIX + jh * 32 + lk * 8);
        }
    }
    __syncthreads();

    for (int jt = 0; jt < 64; jt += 2) {
        attn_step(jt,     kb, vb, Ks[0], Ks[1], vf0, vf1, af, oacc, lsum, ps, l, w, lr, lk, iq, jq);
        attn_step(jt + 1, kb, vb, Ks[1], Ks[0], vf1, vf0, af, oacc, lsum, ps, l, w, lr, lk, iq, jq);
    }

    // ---- row-sum reduce: over lr (16 lanes), then over the 4 jq-waves ----
#pragma unroll
    for (int m = 1; m <= 8; m <<= 1)
#pragma unroll
        for (int r = 0; r < 4; ++r)
            lsum[r] += __shfl_xor(lsum[r], m, 64);
    if (lr == 0)
#pragma unroll
        for (int r = 0; r < 4; ++r)
            red[w][iq * 16 + lk * 4 + r] = lsum[r];
    __syncthreads();
    if (tid < 32) {
        int iqq = tid >> 4;
        float t = red[iqq * 4 + 0][tid] + red[iqq * 4 + 1][tid]
                + red[iqq * 4 + 2][tid] + red[iqq * 4 + 3][tid];
        redt[tid] = 1.0f / t;
    }
    __syncthreads();

    _Float16* ob = oT + (long)b * NPIX * CDIM;
#pragma unroll
    for (int mi = 0; mi < 2; ++mi)
#pragma unroll
        for (int r = 0; r < 4; ++r) {
            int row = mi * 16 + lk * 4 + r;
            float rv = redt[row];
#pragma unroll
            for (int ni = 0; ni < 4; ++ni) {
                int c = w * 64 + ni * 16 + lr;
                ob[(long)(i0 + row) * CDIM + c] = (_Float16)(oacc[mi][ni][r] * rv);
            }
        }
}

extern "C" void kernel_launch(void* const* d_in, const int* in_sizes, int n_in,
                              void* d_out, int out_size, void* d_ws, size_t ws_size,
                              hipStream_t stream) {
    const float* x     = (const float*)d_in[0];
    const float* gamma = (const float*)d_in[1];
    const float* beta  = (const float*)d_in[2];
    const float* wq    = (const float*)d_in[3];
    const float* bq    = (const float*)d_in[4];
    const float* wk    = (const float*)d_in[5];
    const float* bk    = (const float*)d_in[6];
    const float* wv    = (const float*)d_in[7];
    const float* bv    = (const float*)d_in[8];
    const float* wo    = (const float*)d_in[9];
    const float* bo    = (const float*)d_in[10];
    float* out = (float*)d_out;

    char* ws = (char*)d_ws;
    float* stats = (float*)ws;
    _Float16* wqb = (_Float16*)(ws + 1024);
    _Float16* wkb = wqb + 262144;
    _Float16* wvb = wkb + 262144;
    _Float16* wob = wvb + 262144;
    _Float16* hT  = wob + 262144;
    const long TSZ = (long)2 * NPIX * CDIM;
    _Float16* qT = hT + TSZ;
    _Float16* kT = qT + TSZ;
    _Float16* vv = kT + TSZ;
    _Float16* oT = vv + TSZ;

    cvt_w<<<dim3(1024), dim3(256), 0, stream>>>(wq, wk, wv, wo, wqb, wkb, wvb, wob);
    stats_kernel<<<dim3(64), dim3(256), 0, stream>>>(x, stats);
    normT_kernel<<<dim3(16, 128, 2), dim3(256), 0, stream>>>(x, stats, gamma, beta, hT);

    const long NC = (long)NPIX * CDIM;
    gemm_bt_kernel<0><<<dim3(4, 32, 2), dim3(256), 0, stream>>>(
        hT, wqb, (void*)qT, bq, nullptr, NPIX, CDIM, CDIM, NC, 0L, NC, 0L);
    gemm_bt_kernel<0><<<dim3(4, 32, 2), dim3(256), 0, stream>>>(
        hT, wkb, (void*)kT, bk, nullptr, NPIX, CDIM, CDIM, NC, 0L, NC, 0L);
    gemm_bt_kernel<1><<<dim3(32, 4, 2), dim3(256), 0, stream>>>(
        wvb, hT, (void*)vv, bv, nullptr, CDIM, NPIX, CDIM, 0L, NC, NC, 0L);

    attn_kernel<<<dim3(128, 2), dim3(512), 0, stream>>>(qT, kT, vv, oT);

    gemm_bt_kernel<2><<<dim3(32, 4, 2), dim3(256), 0, stream>>>(
        wob, oT, (void*)out, bo, x, CDIM, NPIX, CDIM, 0L, NC, NC, NC);
}

// Round 3
// 287.118 us; speedup vs baseline: 1.4317x; 1.4317x over previous
//
#include <hip/hip_runtime.h>
#include <stdint.h>

#define NPIX 4096
#define CDIM 512

typedef _Float16 hv8 __attribute__((ext_vector_type(8)));
typedef float f32x4 __attribute__((ext_vector_type(4)));

__device__ __forceinline__ void lds_direct16(const _Float16* g, _Float16* l) {
    __builtin_amdgcn_global_load_lds(
        (const __attribute__((address_space(1))) void*)g,
        (__attribute__((address_space(3))) void*)l, 16, 0, 0);
}

// ---------------- weight fp32 -> fp16 ----------------
__global__ void cvt_w(const float* __restrict__ s0, const float* __restrict__ s1,
                      const float* __restrict__ s2, const float* __restrict__ s3,
                      _Float16* __restrict__ d0, _Float16* __restrict__ d1,
                      _Float16* __restrict__ d2, _Float16* __restrict__ d3) {
    int i = blockIdx.x * 256 + threadIdx.x;
    d0[i] = (_Float16)s0[i];
    d1[i] = (_Float16)s1[i];
    d2[i] = (_Float16)s2[i];
    d3[i] = (_Float16)s3[i];
}

// ---------------- groupnorm stats: one block per (b,g) ----------------
__global__ void stats_kernel(const float* __restrict__ x, float* __restrict__ stats) {
    int idx = blockIdx.x;
    const float4* base = (const float4*)(x + (long)idx * 16 * NPIX);
    int tid = threadIdx.x;
    float s = 0.f, sq = 0.f;
    for (int it = 0; it < 64; ++it) {
        float4 f = base[it * 256 + tid];
        s  += f.x + f.y + f.z + f.w;
        sq += f.x * f.x + f.y * f.y + f.z * f.z + f.w * f.w;
    }
    __shared__ float rs[256], rq[256];
    rs[tid] = s; rq[tid] = sq;
    __syncthreads();
    for (int st = 128; st > 0; st >>= 1) {
        if (tid < st) { rs[tid] += rs[tid + st]; rq[tid] += rq[tid + st]; }
        __syncthreads();
    }
    if (tid == 0) {
        float mean = rs[0] * (1.0f / 65536.0f);
        float var  = rq[0] * (1.0f / 65536.0f) - mean * mean;
        stats[idx * 2]     = mean;
        stats[idx * 2 + 1] = rsqrtf(var + 1e-6f);
    }
}

// ---------------- normalize + transpose: hT[b][n][c] = GN(x)[b][c][n] ----------------
__global__ void normT_kernel(const float* __restrict__ x, const float* __restrict__ stats,
                             const float* __restrict__ gamma, const float* __restrict__ beta,
                             _Float16* __restrict__ hT) {
    int b = blockIdx.z, c0 = blockIdx.x * 32, n0 = blockIdx.y * 32;
    int tid = threadIdx.x;
    __shared__ float t[32][33];
    int cl = tid >> 5;
    int nl = tid & 31;
    for (int r = 0; r < 4; ++r)
        t[r * 8 + cl][nl] = x[(long)b * CDIM * NPIX + (long)(c0 + r * 8 + cl) * NPIX + n0 + nl];
    __syncthreads();
    for (int r = 0; r < 4; ++r) {
        int nr = r * 8 + cl;
        int c = c0 + nl;
        float m    = stats[(b * 32 + (c >> 4)) * 2];
        float rstd = stats[(b * 32 + (c >> 4)) * 2 + 1];
        float val = (t[nl][nr] - m) * rstd * gamma[c] + beta[c];
        hT[(long)b * NPIX * CDIM + (long)(n0 + nr) * CDIM + c] = (_Float16)val;
    }
}

// ---------------- bt-form GEMM: D[M][N] = A[M][K] * BT[N][K]^T ----------------
template<int EPI>
__launch_bounds__(256, 2)
__global__ void gemm_bt_kernel(const _Float16* __restrict__ A, const _Float16* __restrict__ BT,
                               void* __restrict__ D, const float* __restrict__ bias,
                               const float* __restrict__ resid,
                               int M, int N, int K,
                               long aBatch, long bBatch, long dBatch, long rBatch) {
    const int b = blockIdx.z;
    A  += (long)b * aBatch;
    BT += (long)b * bBatch;
    const int m0 = blockIdx.y * 128;
    const int n0 = blockIdx.x * 128;
    const int tid = threadIdx.x;
    const int l = tid & 63;
    const int w = tid >> 6;
    const int wm = (w >> 1) * 64;
    const int wn = (w & 1) * 64;
    const int lr = l & 15;
    const int lk = l >> 4;
    __shared__ __align__(16) _Float16 As[128 * 32];
    __shared__ __align__(16) _Float16 Bs[128 * 32];
    f32x4 acc[4][4] = {};
    const int nK = K >> 5;
    for (int kt = 0; kt < nK; ++kt) {
        const int kb = kt * 32;
#pragma unroll
        for (int c = 0; c < 2; ++c) {
            int chunk = c * 256 + tid;
            int row = chunk >> 2;
            int k8 = (chunk & 3) * 8;
            _Float16* ldsA = As + (size_t)(c * 256 + (tid & ~63)) * 8;
            _Float16* ldsB = Bs + (size_t)(c * 256 + (tid & ~63)) * 8;
            lds_direct16(A  + (long)(m0 + row) * K + kb + k8, ldsA);
            lds_direct16(BT + (long)(n0 + row) * K + kb + k8, ldsB);
        }
        __syncthreads();
        hv8 af[4], bfr[4];
#pragma unroll
        for (int mi = 0; mi < 4; ++mi)
            af[mi] = *(const hv8*)(As + (size_t)(wm + mi * 16 + lr) * 32 + lk * 8);
#pragma unroll
        for (int ni = 0; ni < 4; ++ni)
            bfr[ni] = *(const hv8*)(Bs + (size_t)(wn + ni * 16 + lr) * 32 + lk * 8);
#pragma unroll
        for (int mi = 0; mi < 4; ++mi)
#pragma unroll
            for (int ni = 0; ni < 4; ++ni)
                acc[mi][ni] = __builtin_amdgcn_mfma_f32_16x16x32_f16(af[mi], bfr[ni], acc[mi][ni], 0, 0, 0);
        __syncthreads();
    }
#pragma unroll
    for (int mi = 0; mi < 4; ++mi)
#pragma unroll
        for (int ni = 0; ni < 4; ++ni)
#pragma unroll
            for (int r = 0; r < 4; ++r) {
                int row = m0 + wm + mi * 16 + lk * 4 + r;
                int col = n0 + wn + ni * 16 + lr;
                float val = acc[mi][ni][r];
                if (EPI == 0) {
                    ((_Float16*)D)[(long)b * dBatch + (long)row * N + col] = (_Float16)(val + bias[col]);
                } else if (EPI == 1) {
                    ((_Float16*)D)[(long)b * dBatch + (long)row * N + col] = (_Float16)(val + bias[row]);
                } else {
                    long idx = (long)row * N + col;
                    ((float*)D)[(long)b * dBatch + idx] =
                        val + bias[row] + resid[(long)b * rBatch + idx];
                }
            }
}

// ---------------- flash attention v3 ----------------
// qT,kT [N][C] fp16, v [C][N] fp16 -> oT [N][C] fp16
// i-tile 32, j-tile 64. 8 waves: wave w -> S quadrant (iq=w>>2, jq=w&3).
// K double-buffered in LDS via global_load_lds (source-side XOR swizzle).
// Q fragments in registers (64 VGPR). V fragments single-buffered in registers,
// issued at top of step (T14) and BEFORE K staging so the pre-PV wait is
// vmcnt(8), keeping the 8 staging loads in flight across the mid-barrier.
__launch_bounds__(512, 2)
__global__ void attn_kernel(const _Float16* __restrict__ qT, const _Float16* __restrict__ kT,
                            const _Float16* __restrict__ v, _Float16* __restrict__ oT) {
    __shared__ __align__(16) _Float16 Ks[2][64 * 512];   // 128 KB, XOR-swizzled rows
    __shared__ __align__(16) _Float16 ps[32 * 64];       // 4 KB, XOR-swizzled
    __shared__ float red[8][32];
    __shared__ float redt[32];

    const int b = blockIdx.y;
    const int i0 = blockIdx.x * 32;
    const int tid = threadIdx.x;
    const int l = tid & 63, w = tid >> 6;
    const int lr = l & 15, lk = l >> 4;
    const int iq = w >> 2, jq = w & 3;

    const _Float16* qb = qT + (long)b * NPIX * CDIM;
    const _Float16* kb = kT + (long)b * NPIX * CDIM;
    const _Float16* vb = v  + (long)b * CDIM * NPIX;

    // Q fragments in registers: wave's 16 rows (iq*16+lr), all 16 k-chunks
    hv8 af[16];
    {
        const _Float16* qr = qb + (long)(i0 + iq * 16 + lr) * CDIM + lk * 8;
#pragma unroll
        for (int kk = 0; kk < 16; ++kk)
            af[kk] = *(const hv8*)(qr + kk * 32);
    }

    f32x4 oacc[2][4] = {};
    float lsum[4] = {};
    hv8 vf[4][2];

    // prologue: stage K tile 0 into Ks[0]
#pragma unroll
    for (int q = 0; q < 8; ++q) {
        int j = w * 8 + q;
        int cc = l ^ (j & 7);
        lds_direct16(kb + (long)j * CDIM + cc * 8, &Ks[0][(w * 8 + q) * 512]);
    }
    __syncthreads();

    const float scale = 0.044194173824159216f;   // 1/sqrt(512)

    for (int jt = 0; jt < 64; ++jt) {
        const long j0 = (long)jt * 64;
        _Float16* kcur = Ks[jt & 1];
        _Float16* knxt = Ks[(jt + 1) & 1];

        // ---- (1) V fragment loads for THIS step (issued first!) ----
#pragma unroll
        for (int ni = 0; ni < 4; ++ni) {
            int c = w * 64 + ni * 16 + lr;
#pragma unroll
            for (int jh = 0; jh < 2; ++jh)
                vf[ni][jh] = *(const hv8*)(vb + (long)c * NPIX + j0 + jh * 32 + lk * 8);
        }
        __builtin_amdgcn_sched_barrier(0);

        // ---- (2) K staging for NEXT step (stays in flight past mid-barrier) ----
        if (jt < 63) {
#pragma unroll
            for (int q = 0; q < 8; ++q) {
                int j = w * 8 + q;
                int cc = l ^ (j & 7);
                lds_direct16(kb + (j0 + 64 + j) * CDIM + cc * 8, knxt + (w * 8 + q) * 512);
            }
        }
        __builtin_amdgcn_sched_barrier(0);

        // ---- (3) QK: one 16x16 quadrant per wave ----
        f32x4 s = {};
        {
            const char* kbase = (const char*)kcur;
            const int j = jq * 16 + lr;
            const uint32_t sw = (uint32_t)((j & 7) << 4);
#pragma unroll
            for (int kk = 0; kk < 16; ++kk) {
                uint32_t off = ((uint32_t)(j * 1024 + kk * 64 + lk * 16)) ^ sw;
                hv8 bf = *(const hv8*)(kbase + off);
                s = __builtin_amdgcn_mfma_f32_16x16x32_f16(af[kk], bf, s, 0, 0, 0);
            }
        }

        // ---- (4) exp + P write (swizzled) ----
#pragma unroll
        for (int r = 0; r < 4; ++r) {
            float p = __expf(s[r] * scale);
            lsum[r] += p;
            int i = iq * 16 + lk * 4 + r;
            int j = jq * 16 + lr;
            uint32_t off = ((uint32_t)(i * 128 + j * 2)) ^ ((uint32_t)((i & 7) << 4));
            *(_Float16*)((char*)ps + off) = (_Float16)p;
        }

        // ---- (5) mid barrier: drain LDS only; K staging stays outstanding ----
        asm volatile("s_waitcnt lgkmcnt(0)" ::: "memory");
        __builtin_amdgcn_sched_barrier(0);
        __builtin_amdgcn_s_barrier();

        // ---- (6) PV: O[32 rows][w's 64 c-cols] += P * V^T ----
#pragma unroll
        for (int jh = 0; jh < 2; ++jh) {
            hv8 pa[2];
#pragma unroll
            for (int mi = 0; mi < 2; ++mi) {
                int i = mi * 16 + lr;
                uint32_t off = ((uint32_t)(i * 128 + jh * 64 + lk * 16)) ^ ((uint32_t)((i & 7) << 4));
                pa[mi] = *(const hv8*)((const char*)ps + off);
            }
#pragma unroll
            for (int ni = 0; ni < 4; ++ni)
#pragma unroll
                for (int mi = 0; mi < 2; ++mi)
                    oacc[mi][ni] = __builtin_amdgcn_mfma_f32_16x16x32_f16(pa[mi], vf[ni][jh], oacc[mi][ni], 0, 0, 0);
        }

        // ---- (7) full drain: staging for next tile complete, ps reusable ----
        __syncthreads();
    }

    // ---- row-sum reduce: over lr (16 lanes), then over the 4 jq-waves ----
#pragma unroll
    for (int m = 1; m <= 8; m <<= 1)
#pragma unroll
        for (int r = 0; r < 4; ++r)
            lsum[r] += __shfl_xor(lsum[r], m, 64);
    if (lr == 0)
#pragma unroll
        for (int r = 0; r < 4; ++r)
            red[w][iq * 16 + lk * 4 + r] = lsum[r];
    __syncthreads();
    if (tid < 32) {
        int iqq = tid >> 4;
        float t = red[iqq * 4 + 0][tid] + red[iqq * 4 + 1][tid]
                + red[iqq * 4 + 2][tid] + red[iqq * 4 + 3][tid];
        redt[tid] = 1.0f / t;
    }
    __syncthreads();

    _Float16* ob = oT + (long)b * NPIX * CDIM;
#pragma unroll
    for (int mi = 0; mi < 2; ++mi)
#pragma unroll
        for (int r = 0; r < 4; ++r) {
            int row = mi * 16 + lk * 4 + r;
            float rv = redt[row];
#pragma unroll
            for (int ni = 0; ni < 4; ++ni) {
                int c = w * 64 + ni * 16 + lr;
                ob[(long)(i0 + row) * CDIM + c] = (_Float16)(oacc[mi][ni][r] * rv);
            }
        }
}

extern "C" void kernel_launch(void* const* d_in, const int* in_sizes, int n_in,
                              void* d_out, int out_size, void* d_ws, size_t ws_size,
                              hipStream_t stream) {
    const float* x     = (const float*)d_in[0];
    const float* gamma = (const float*)d_in[1];
    const float* beta  = (const float*)d_in[2];
    const float* wq    = (const float*)d_in[3];
    const float* bq    = (const float*)d_in[4];
    const float* wk    = (const float*)d_in[5];
    const float* bk    = (const float*)d_in[6];
    const float* wv    = (const float*)d_in[7];
    const float* bv    = (const float*)d_in[8];
    const float* wo    = (const float*)d_in[9];
    const float* bo    = (const float*)d_in[10];
    float* out = (float*)d_out;

    char* ws = (char*)d_ws;
    float* stats = (float*)ws;
    _Float16* wqb = (_Float16*)(ws + 1024);
    _Float16* wkb = wqb + 262144;
    _Float16* wvb = wkb + 262144;
    _Float16* wob = wvb + 262144;
    _Float16* hT  = wob + 262144;
    const long TSZ = (long)2 * NPIX * CDIM;
    _Float16* qT = hT + TSZ;
    _Float16* kT = qT + TSZ;
    _Float16* vv = kT + TSZ;
    _Float16* oT = vv + TSZ;

    cvt_w<<<dim3(1024), dim3(256), 0, stream>>>(wq, wk, wv, wo, wqb, wkb, wvb, wob);
    stats_kernel<<<dim3(64), dim3(256), 0, stream>>>(x, stats);
    normT_kernel<<<dim3(16, 128, 2), dim3(256), 0, stream>>>(x, stats, gamma, beta, hT);

    const long NC = (long)NPIX * CDIM;
    gemm_bt_kernel<0><<<dim3(4, 32, 2), dim3(256), 0, stream>>>(
        hT, wqb, (void*)qT, bq, nullptr, NPIX, CDIM, CDIM, NC, 0L, NC, 0L);
    gemm_bt_kernel<0><<<dim3(4, 32, 2), dim3(256), 0, stream>>>(
        hT, wkb, (void*)kT, bk, nullptr, NPIX, CDIM, CDIM, NC, 0L, NC, 0L);
    gemm_bt_kernel<1><<<dim3(32, 4, 2), dim3(256), 0, stream>>>(
        wvb, hT, (void*)vv, bv, nullptr, CDIM, NPIX, CDIM, 0L, NC, NC, 0L);

    attn_kernel<<<dim3(128, 2), dim3(512), 0, stream>>>(qT, kT, vv, oT);

    gemm_bt_kernel<2><<<dim3(32, 4, 2), dim3(256), 0, stream>>>(
        wob, oT, (void*)out, bo, x, CDIM, NPIX, CDIM, 0L, NC, NC, NC);
}